// Round 4
// baseline (1879.810 us; speedup 1.0000x reference)
//
#include <hip/hip_runtime.h>
#include <hip/hip_bf16.h>

// ---------------- constants ----------------
#define L1X   1500   // raw sequence length
#define L1P   751    // pool1 length
#define C1    64
#define L2P   377    // pool2 length
#define C2    128
#define L3P   191    // pool3 length
#define C3    128
#define FEATK 24448  // C3*L3P
#define D2    256
#define HIDN  128

// map2 GEMM config
#define SK      32            // split-K ways
#define KCHUNK  764           // FEATK / SK = 191*4
#define NIT     191           // KCHUNK / 4

#define TSTR  68              // padded LDS tile stride (68 floats = 272B, 16B-aligned rows)

// =====================================================================
// K2: fused conv1(+bn+relu+pool) recompute  ->  conv2+bn2+relu+pool
// grid: rows_in_chunk * 12 tiles, block 512 (128 ch x 4 pos-groups)
// =====================================================================
__global__ __launch_bounds__(512)
void k_conv12(const float* __restrict__ X, const float* __restrict__ w1,
              const float* __restrict__ bn1, const float* __restrict__ w2,
              const float* __restrict__ bn2, float* __restrict__ pool2,
              int b_off)
{
    const int blk  = blockIdx.x;
    const int b    = b_off + blk / 12;
    const int i0   = (blk % 12) * 32;

    __shared__ __align__(16) float xrow[L1X];
    __shared__ __align__(16) float t1[C1 * TSTR];

    for (int e = threadIdx.x; e < L1X; e += 512) xrow[e] = X[(size_t)b * L1X + e];
    __syncthreads();

    // pool1 tile: t in [tb, tb+65]
    const int tb = 2 * i0 - 3;
    for (int e = threadIdx.x; e < C1 * 66; e += 512) {
        int c = e / 66, j = e - c * 66;
        int t = tb + j;
        float val = 0.f;
        if (t >= 0 && t < L1P) {
            float wk0 = w1[c*3+0], wk1 = w1[c*3+1], wk2 = w1[c*3+2];
            float s    = bn1[c] * rsqrtf(bn1[192+c] + 1e-5f);
            float bias = bn1[64+c] - bn1[128+c] * s;
            float v0 = 0.f, v1 = 0.f;
            if (t >= 1) {               // conv pos l = 2t-1  (reads x[2t-2..2t])
                int l = 2*t - 1;
                float x2 = (l+1 < L1X) ? xrow[l+1] : 0.f;
                float cv = wk0*xrow[l-1] + wk1*xrow[l] + wk2*x2;
                v0 = fmaxf(cv*s + bias, 0.f);
            }
            if (t <= 749) {             // conv pos l = 2t    (reads x[2t-1..2t+1])
                int l = 2*t;
                float x0 = (l-1 >= 0) ? xrow[l-1] : 0.f;
                float cv = wk0*x0 + wk1*xrow[l] + wk2*xrow[l+1];
                v1 = fmaxf(cv*s + bias, 0.f);
            }
            val = fmaxf(v0, v1);
        }
        t1[c*TSTR + j] = val;
    }
    __syncthreads();

    const int c    = threadIdx.x & 127;   // out-channel
    const int grp  = threadIdx.x >> 7;    // position group (0..3)
    const int lbase = 16 * grp;

    float acc0[8] = {0,0,0,0,0,0,0,0};
    float acc1[8] = {0,0,0,0,0,0,0,0};
    const float* Wc = w2 + c * (C1*3);

    for (int icg = 0; icg < C1; icg += 4) {
        // 12 contiguous weights = 4 input channels x 3 taps
        float4 wA = *(const float4*)(Wc + icg*3);
        float4 wB = *(const float4*)(Wc + icg*3 + 4);
        float4 wC = *(const float4*)(Wc + icg*3 + 8);
        float w[4][3] = {{wA.x,wA.y,wA.z},{wA.w,wB.x,wB.y},
                         {wB.z,wB.w,wC.x},{wC.y,wC.z,wC.w}};
        #pragma unroll
        for (int s = 0; s < 4; ++s) {
            const float* rowp = &t1[(icg + s)*TSTR + lbase];
            float4 x0 = *(const float4*)(rowp);
            float4 x1 = *(const float4*)(rowp + 4);
            float4 x2 = *(const float4*)(rowp + 8);
            float4 x3 = *(const float4*)(rowp + 12);
            float2 x4 = *(const float2*)(rowp + 16);
            float xv[18] = {x0.x,x0.y,x0.z,x0.w, x1.x,x1.y,x1.z,x1.w,
                            x2.x,x2.y,x2.z,x2.w, x3.x,x3.y,x3.z,x3.w,
                            x4.x,x4.y};
            #pragma unroll
            for (int k = 0; k < 3; ++k) {
                float wv = w[s][k];
                #pragma unroll
                for (int j = 0; j < 8; ++j) {
                    acc0[j] += wv * xv[2*j + k];
                    acc1[j] += wv * xv[2*j + k + 1];
                }
            }
        }
    }
    float s2 = bn2[c] * rsqrtf(bn2[384+c] + 1e-5f);
    float b2 = bn2[128+c] - bn2[256+c] * s2;
    #pragma unroll
    for (int j = 0; j < 8; ++j) {
        int i = i0 + grp*8 + j;
        if (i < L2P) {
            float v0 = (i >= 1) ? fmaxf(acc0[j]*s2 + b2, 0.f) : 0.f;
            float v1 = fmaxf(acc1[j]*s2 + b2, 0.f);
            pool2[((size_t)(b - b_off)*C2 + c)*L2P + i] = fmaxf(v0, v1);
        }
    }
}

// =====================================================================
// K3: conv3+bn3+relu+pool. grid: rows_in_chunk * 6 tiles, block 512
// =====================================================================
__global__ __launch_bounds__(512)
void k_conv3(const float* __restrict__ pool2, const float* __restrict__ w3,
             const float* __restrict__ bn3, float* __restrict__ pool3, int b_off)
{
    const int blk = blockIdx.x;
    const int bl  = blk / 6;              // local row in chunk
    const int b   = b_off + bl;           // global row
    const int i0  = (blk % 6) * 32;

    __shared__ __align__(16) float t2[C2 * TSTR];
    const int tb = 2*i0 - 4;
    for (int e = threadIdx.x; e < C2*66; e += 512) {
        int ic = e / 66, j = e - ic*66;
        int t = tb + j;
        t2[ic*TSTR + j] = (t >= 0 && t < L2P) ? pool2[((size_t)bl*C2 + ic)*L2P + t] : 0.f;
    }
    __syncthreads();

    const int c    = threadIdx.x & 127;
    const int grp  = threadIdx.x >> 7;    // 0..3
    const int lbase = 16 * grp;

    float acc0[8] = {0,0,0,0,0,0,0,0};
    float acc1[8] = {0,0,0,0,0,0,0,0};
    const float* Wc = w3 + c * (C2*3);

    for (int icg = 0; icg < C2; icg += 4) {
        float4 wA = *(const float4*)(Wc + icg*3);
        float4 wB = *(const float4*)(Wc + icg*3 + 4);
        float4 wC = *(const float4*)(Wc + icg*3 + 8);
        float w[4][3] = {{wA.x,wA.y,wA.z},{wA.w,wB.x,wB.y},
                         {wB.z,wB.w,wC.x},{wC.y,wC.z,wC.w}};
        #pragma unroll
        for (int s = 0; s < 4; ++s) {
            const float* rowp = &t2[(icg + s)*TSTR + lbase];
            float4 x0 = *(const float4*)(rowp);
            float4 x1 = *(const float4*)(rowp + 4);
            float4 x2 = *(const float4*)(rowp + 8);
            float4 x3 = *(const float4*)(rowp + 12);
            float2 x4 = *(const float2*)(rowp + 16);
            float xv[18] = {x0.x,x0.y,x0.z,x0.w, x1.x,x1.y,x1.z,x1.w,
                            x2.x,x2.y,x2.z,x2.w, x3.x,x3.y,x3.z,x3.w,
                            x4.x,x4.y};
            #pragma unroll
            for (int k = 0; k < 3; ++k) {
                float wv = w[s][k];
                #pragma unroll
                for (int j = 0; j < 8; ++j) {
                    acc0[j] += wv * xv[2*j + k];
                    acc1[j] += wv * xv[2*j + k + 1];
                }
            }
        }
    }
    float s3 = bn3[c] * rsqrtf(bn3[384+c] + 1e-5f);
    float b3 = bn3[128+c] - bn3[256+c] * s3;
    #pragma unroll
    for (int j = 0; j < 8; ++j) {
        int i = i0 + grp*8 + j;
        if (i < L3P) {
            float v0 = (i >= 1) ? fmaxf(acc0[j]*s3 + b3, 0.f) : 0.f;
            float v1 = fmaxf(acc1[j]*s3 + b3, 0.f);
            pool3[((size_t)b*C3 + c)*L3P + i] = fmaxf(v0, v1);
        }
    }
}

// =====================================================================
// K4a: split-K GEMM partials: partial[kt] = A[768,KCHUNK@kt] @ W[.,256]
// tile 64x128, 256 threads, 4x8 per thread, Kb=4, double-buffered LDS
// grid: 12 (M) * 2 (N) * 32 (K) = 768 blocks
// =====================================================================
__global__ __launch_bounds__(256)
void k_map2_gemm(const float* __restrict__ A, const float* __restrict__ W,
                 float* __restrict__ part)
{
    const int bid = blockIdx.x;
    const int kt  = bid / 24;
    const int rem = bid % 24;
    const int mt  = rem >> 1;
    const int nt  = rem & 1;

    __shared__ __align__(16) float At[2][4][64];
    __shared__ __align__(16) float Bt[2][4][128];

    const int tid = threadIdx.x;
    const int m0  = (tid & 15) * 4;       // rows m0..m0+3
    const int n0  = (tid >> 4) * 8;      // cols n0..n0+7

    // A fill: row = tid>>2 (0..63), kk = tid&3 (coalesced 16B per row)
    const int arow = tid >> 2;
    const int akk  = tid & 3;
    // B fill: krow = tid>>6 (0..3), col2 = (tid&63)*2 (coalesced 512B per k-row)
    const int bk   = tid >> 6;
    const int bc   = (tid & 63) * 2;

    const float* Aptr = A + (size_t)(mt * 64 + arow) * FEATK + kt * KCHUNK + akk;
    const float* Bptr = W + (size_t)(kt * KCHUNK + bk) * D2 + nt * 128 + bc;

    float acc[4][8];
    #pragma unroll
    for (int i = 0; i < 4; ++i)
        #pragma unroll
        for (int j = 0; j < 8; ++j) acc[i][j] = 0.f;

    // prologue: stage it=0
    float  a_reg = Aptr[0];
    float2 b_reg = *(const float2*)(Bptr);
    At[0][akk][arow] = a_reg;
    *(float2*)&Bt[0][bk][bc] = b_reg;

    int cur = 0;
    for (int it = 0; it < NIT; ++it) {
        __syncthreads();
        if (it + 1 < NIT) {   // prefetch next K-slice into regs (hides under compute)
            a_reg = Aptr[(it + 1) * 4];
            b_reg = *(const float2*)(Bptr + (size_t)(it + 1) * 4 * D2);
        }
        #pragma unroll
        for (int k = 0; k < 4; ++k) {
            float4 a0 = *(const float4*)&At[cur][k][m0];
            float4 b0 = *(const float4*)&Bt[cur][k][n0];
            float4 b1 = *(const float4*)&Bt[cur][k][n0 + 4];
            float av[4] = {a0.x, a0.y, a0.z, a0.w};
            float bv[8] = {b0.x, b0.y, b0.z, b0.w, b1.x, b1.y, b1.z, b1.w};
            #pragma unroll
            for (int i = 0; i < 4; ++i)
                #pragma unroll
                for (int j = 0; j < 8; ++j)
                    acc[i][j] += av[i] * bv[j];
        }
        if (it + 1 < NIT) {   // write prefetched slice into the other buffer
            At[cur ^ 1][akk][arow] = a_reg;
            *(float2*)&Bt[cur ^ 1][bk][bc] = b_reg;
        }
        cur ^= 1;
    }

    // store partial tile
    float* P = part + ((size_t)kt * 768) * D2;
    #pragma unroll
    for (int i = 0; i < 4; ++i) {
        int grow = mt * 64 + m0 + i;
        float* dst = P + (size_t)grow * D2 + nt * 128 + n0;
        *(float4*)(dst)     = make_float4(acc[i][0], acc[i][1], acc[i][2], acc[i][3]);
        *(float4*)(dst + 4) = make_float4(acc[i][4], acc[i][5], acc[i][6], acc[i][7]);
    }
}

// =====================================================================
// K4b: reduce split-K partials + bias + BN + positional encoding
// grid 768 (one row per block), block 256 (one col per thread)
// =====================================================================
__global__ __launch_bounds__(256)
void k_map2fin(const float* __restrict__ part, const float* __restrict__ mb,
               const float* __restrict__ bn, float* __restrict__ out)
{
    const int row = blockIdx.x;
    const int n   = threadIdx.x;
    float acc = 0.f;
    #pragma unroll
    for (int kt = 0; kt < SK; ++kt)
        acc += part[((size_t)kt * 768 + row) * D2 + n];

    float s    = bn[n] * rsqrtf(bn[768+n] + 1e-5f);
    float beta = bn[256+n];
    float mu   = bn[512+n];
    float bias = mb[n];
    int   jj   = n >> 1;
    float freq = expf((float)(2*jj) * (-4.605170185988092f / 256.f)); // -ln(100)/256
    int   t    = (row >> 2) % 6;
    float ang  = (float)t * freq;
    float pe   = (n & 1) ? cosf(ang) : sinf(ang);
    out[(size_t)row*D2 + n] = (acc + bias - mu)*s + beta + pe;
}

// =====================================================================
// K5: MPNN block (win=2). one block per graph, block 256
// =====================================================================
__global__ __launch_bounds__(256)
void k_mpnn(const float* __restrict__ a_pe, const float* __restrict__ gw,
            const float* __restrict__ gb, const float* __restrict__ bnA,
            const float* __restrict__ tw, const float* __restrict__ tb_,
            const float* __restrict__ bnM, float* __restrict__ feats,
            int nw, int stride, int base)
{
    const int g  = blockIdx.x;
    const int b  = g / nw, wi = g % nw;
    const int tid = threadIdx.x;

    __shared__ float Xc[8][256];
    __shared__ float Xb[8][256];
    __shared__ float Fs[8][256];
    __shared__ float Adj[8][8];
    __shared__ float hsm[8][128];

    for (int e = tid; e < 2048; e += 256) {
        int nn = e >> 8, d = e & 255;
        int tt = nn >> 2, sn = nn & 3;
        float v = a_pe[(((size_t)(b*6) + (wi*stride + tt))*4 + sn)*D2 + d];
        Xc[nn][d] = v;
        float s = bnA[d] * rsqrtf(bnA[768+d] + 1e-5f);
        Xb[nn][d] = (v - bnA[512+d])*s + bnA[256+d];
    }
    __syncthreads();

    {   // f = Xc @ gw + gb
        const int d = tid;
        #pragma unroll
        for (int nn = 0; nn < 8; ++nn) {
            float acc = gb[d];
            for (int k = 0; k < 256; ++k) acc += Xc[nn][k] * gw[(size_t)k*D2 + d];
            Fs[nn][d] = acc;
        }
    }
    __syncthreads();

    if (tid < 64) {   // raw adjacency + diag suppress + leaky
        int nn = tid >> 3, m = tid & 7;
        float s = 0.f;
        for (int d = 0; d < 256; ++d) s += Fs[nn][d] * Fs[m][d];
        if (nn == m) s -= 1e8f;
        s = (s > 0.f) ? s : 0.01f*s;
        Adj[nn][m] = s;
    }
    __syncthreads();

    if (tid < 8) {    // softmax row + eye + decay mask
        int nn = tid;
        float mx = -1e30f;
        for (int m = 0; m < 8; ++m) mx = fmaxf(mx, Adj[nn][m]);
        float ex[8]; float sum = 0.f;
        for (int m = 0; m < 8; ++m) { ex[m] = expf(Adj[nn][m]-mx); sum += ex[m]; }
        float inv = 1.f / sum;
        for (int m = 0; m < 8; ++m) {
            float v = ex[m]*inv + ((nn==m) ? 1.f : 0.f);
            v *= ((nn>>2) == (m>>2)) ? 1.f : 0.7f;   // 0.7^|dt|, dt in {0,1}
            Adj[nn][m] = v;
        }
    }
    __syncthreads();

    {   // hmid = Adj @ Xb   (store into Fs, no longer needed)
        const int d = tid;
        float hm[8];
        #pragma unroll
        for (int nn = 0; nn < 8; ++nn) {
            float a = 0.f;
            #pragma unroll
            for (int m = 0; m < 8; ++m) a += Adj[nn][m] * Xb[m][d];
            hm[nn] = a;
        }
        #pragma unroll
        for (int nn = 0; nn < 8; ++nn) Fs[nn][d] = hm[nn];
    }
    __syncthreads();

    {   // h = leaky(BN(hmid @ tw + tb))
        const int o = tid & 127, half = tid >> 7;
        float ms  = bnM[o] * rsqrtf(bnM[384+o] + 1e-5f);
        float mbe = bnM[128+o], mmu = bnM[256+o];
        #pragma unroll
        for (int q = 0; q < 4; ++q) {
            int nn = half + 2*q;
            float acc = tb_[o];
            for (int d = 0; d < 256; ++d) acc += Fs[nn][d] * tw[(size_t)d*HIDN + o];
            float y = (acc - mmu)*ms + mbe;
            hsm[nn][o] = (y > 0.f) ? y : 0.01f*y;
        }
    }
    __syncthreads();

    for (int e = tid; e < 512; e += 256) {   // mean over window-time, write feats
        int sn = e >> 7, o = e & 127;
        feats[(size_t)b*4096 + base + (wi*4 + sn)*HIDN + o] =
            0.5f * (hsm[sn][o] + hsm[4+sn][o]);
    }
}

// =====================================================================
// K6: FC head, one block per batch row
// =====================================================================
__global__ __launch_bounds__(256)
void k_fc(const float* __restrict__ feats,
          const float* __restrict__ w1f, const float* __restrict__ b1f,
          const float* __restrict__ w2f, const float* __restrict__ b2f,
          const float* __restrict__ w3f, const float* __restrict__ b3f,
          const float* __restrict__ w4f, const float* __restrict__ b4f,
          float* __restrict__ out)
{
    const int b = blockIdx.x;
    __shared__ float row[4096];
    __shared__ float h1[256], h2[256], h3[128];
    for (int e = threadIdx.x; e < 4096; e += 256) row[e] = feats[(size_t)b*4096 + e];
    __syncthreads();
    const int n = threadIdx.x;
    {
        float acc = b1f[n];
        for (int f = 0; f < 4096; ++f) acc += row[f] * w1f[(size_t)f*256 + n];
        h1[n] = fmaxf(acc, 0.f);
    }
    __syncthreads();
    {
        float acc = b2f[n];
        for (int k = 0; k < 256; ++k) acc += h1[k] * w2f[(size_t)k*256 + n];
        h2[n] = fmaxf(acc, 0.f);
    }
    __syncthreads();
    if (n < 128) {
        float acc = b3f[n];
        for (int k = 0; k < 256; ++k) acc += h2[k] * w3f[(size_t)k*128 + n];
        h3[n] = fmaxf(acc, 0.f);
    }
    __syncthreads();
    if (n < 5) {
        float acc = b4f[n];
        for (int k = 0; k < 128; ++k) acc += h3[k] * w4f[(size_t)k*5 + n];
        out[b*5 + n] = acc;
    }
}

// =====================================================================
extern "C" void kernel_launch(void* const* d_in, const int* in_sizes, int n_in,
                              void* d_out, int out_size, void* d_ws, size_t ws_size,
                              hipStream_t stream)
{
    const float* X      = (const float*)d_in[0];
    const float* w1     = (const float*)d_in[1];
    const float* bn1    = (const float*)d_in[2];
    const float* w2     = (const float*)d_in[3];
    const float* bn2    = (const float*)d_in[4];
    const float* w3     = (const float*)d_in[5];
    const float* bn3    = (const float*)d_in[6];
    const float* map2w  = (const float*)d_in[7];
    const float* map2b  = (const float*)d_in[8];
    const float* bnm2   = (const float*)d_in[9];
    const float* g1w    = (const float*)d_in[10];
    const float* g1b    = (const float*)d_in[11];
    const float* bnA1   = (const float*)d_in[12];
    const float* th1w   = (const float*)d_in[13];
    const float* th1b   = (const float*)d_in[14];
    const float* bnM1   = (const float*)d_in[15];
    const float* g2w    = (const float*)d_in[16];
    const float* g2b    = (const float*)d_in[17];
    const float* bnA2   = (const float*)d_in[18];
    const float* th2w   = (const float*)d_in[19];
    const float* th2b   = (const float*)d_in[20];
    const float* bnM2   = (const float*)d_in[21];
    const float* fc1w   = (const float*)d_in[22];
    const float* fc1b   = (const float*)d_in[23];
    const float* fc2w   = (const float*)d_in[24];
    const float* fc2b   = (const float*)d_in[25];
    const float* fc3w   = (const float*)d_in[26];
    const float* fc3b   = (const float*)d_in[27];
    const float* fc4w   = (const float*)d_in[28];
    const float* fc4b   = (const float*)d_in[29];
    float* out = (float*)d_out;

    float* ws = (float*)d_ws;
    const size_t N_P2C = (size_t)192 * C2 * L2P;    // 9,265,152 floats (37 MB)
    const size_t N_P3  = (size_t)768 * C3 * L3P;    // 18,776,064 floats (75 MB)
    float* pool2c = ws;
    float* pool3  = ws + N_P2C;
    float* a_pe   = pool3 + N_P3;
    float* feats  = a_pe + (size_t)768 * D2;
    // split-K partials alias pool2c (free after conv loop): 32*768*256 = 6.29M < 9.27M floats
    float* part   = ws;

    for (int boff = 0; boff < 768; boff += 192) {
        hipLaunchKernelGGL(k_conv12, dim3(192*12), dim3(512), 0, stream,
                           X, w1, bn1, w2, bn2, pool2c, boff);
        hipLaunchKernelGGL(k_conv3, dim3(192*6), dim3(512), 0, stream,
                           pool2c, w3, bn3, pool3, boff);
    }
    hipLaunchKernelGGL(k_map2_gemm, dim3(768), dim3(256), 0, stream,
                       pool3, map2w, part);
    hipLaunchKernelGGL(k_map2fin, dim3(768), dim3(256), 0, stream,
                       part, map2b, bnm2, a_pe);
    hipLaunchKernelGGL(k_mpnn, dim3(160), dim3(256), 0, stream,
                       a_pe, g1w, g1b, bnA1, th1w, th1b, bnM1, feats, 5, 1, 0);
    hipLaunchKernelGGL(k_mpnn, dim3(96), dim3(256), 0, stream,
                       a_pe, g2w, g2b, bnA2, th2w, th2b, bnM2, feats, 3, 2, 2560);
    hipLaunchKernelGGL(k_fc, dim3(32), dim3(256), 0, stream,
                       feats, fc1w, fc1b, fc2w, fc2b, fc3w, fc3b, fc4w, fc4b, out);
}

// Round 5
// 790.642 us; speedup vs baseline: 2.3776x; 2.3776x over previous
//
#include <hip/hip_runtime.h>
#include <hip/hip_bf16.h>

// ---------------- constants ----------------
#define L1X   1500   // raw sequence length
#define L1P   751    // pool1 length (t in [0,750])
#define C1    64
#define L2P   377    // pool2 length
#define C2    128
#define L3P   191    // pool3 length
#define C3    128
#define FEATK 24448  // L3P*C3 (stored [i][c] -> f' = i*128 + c)
#define D2    256
#define HIDN  128

// map2 GEMM config
#define SK      32            // split-K ways
#define KCHUNK  764           // FEATK / SK = 191*4
#define NIT     191           // KCHUNK / 4

typedef __attribute__((ext_vector_type(8))) short bf16x8;
typedef __attribute__((ext_vector_type(4))) float f32x4;

__device__ __forceinline__ short f2bf(float x) {
    union { float f; unsigned u; } v; v.f = x;
    unsigned r = (v.u + 0x7FFFu + ((v.u >> 16) & 1u)) >> 16;
    return (short)r;
}
__device__ __forceinline__ float bf2f(short s) {
    union { float f; unsigned u; } v; v.u = ((unsigned)(unsigned short)s) << 16;
    return v.f;
}

// =====================================================================
// Weight prep: w[OC=128][IC][3] fp32 -> Wt[tap][kb][sub][c][8] bf16 hi/lo
// frag-contiguous for b-operand loads (n = c = lane&15, k = kb*32+sub*8+i)
// =====================================================================
template<int IC, int KB>
__global__ __launch_bounds__(256)
void k_wprep(const float* __restrict__ w, short* __restrict__ WtHi,
             short* __restrict__ WtLo)
{
    int idx = blockIdx.x * 256 + threadIdx.x;
    if (idx >= 3 * KB * 4 * 128 * 8) return;
    int i    = idx & 7;
    int rest = idx >> 3;
    int c    = rest & 127; rest >>= 7;
    int sub  = rest & 3;   rest >>= 2;
    int kb   = rest % KB;
    int tap  = rest / KB;
    int ic   = kb * 32 + sub * 8 + i;
    float x  = w[(c * IC + ic) * 3 + tap];
    short h  = f2bf(x);
    WtHi[idx] = h;
    WtLo[idx] = f2bf(x - bf2f(h));
}

// =====================================================================
// Shared MFMA conv core. Block = 256 thr (4 waves). Output tile:
// 128 conv positions [P0, P0+127] x 128 channels. Wave w owns 32 pos.
// Input tile in LDS: [130 rows][IC] bf16 hi/lo, chunk-swizzled:
//   elem off = r*IC + ((logical_chunk ^ (r&7))*8 + (ic&7))
// Epilogue: BN + relu + pool(2,2,pad1) + store [i][c] fp32.
// =====================================================================
template<int IC, int KB, int CONVLEN, int POOLLEN>
__device__ __forceinline__
void conv_mfma_core(const short* __restrict__ WtHi, const short* __restrict__ WtLo,
                    const short* lhi, const short* llo,
                    const float* sc, const float* bc,
                    float* __restrict__ outp, int P0)
{
    const int lane = threadIdx.x & 63;
    const int wave = threadIdx.x >> 6;
    const int l15  = lane & 15;
    const int sub  = lane >> 4;

    f32x4 acc[2][8];
    #pragma unroll
    for (int mf = 0; mf < 2; ++mf)
        #pragma unroll
        for (int nf = 0; nf < 8; ++nf)
            acc[mf][nf] = (f32x4){0.f, 0.f, 0.f, 0.f};

    #pragma unroll
    for (int tap = 0; tap < 3; ++tap) {
        #pragma unroll
        for (int kb = 0; kb < KB; ++kb) {
            bf16x8 ah[2], al[2];
            #pragma unroll
            for (int mf = 0; mf < 2; ++mf) {
                int r = wave * 32 + mf * 16 + l15 + tap;      // LDS input row
                int chunk = (kb * 4 + sub) ^ (r & 7);
                int off = r * IC + chunk * 8;
                ah[mf] = *(const bf16x8*)(lhi + off);
                al[mf] = *(const bf16x8*)(llo + off);
            }
            const short* wbh = WtHi + (size_t)(((tap * KB + kb) * 4 + sub) * 128) * 8;
            const short* wbl = WtLo + (size_t)(((tap * KB + kb) * 4 + sub) * 128) * 8;
            #pragma unroll
            for (int nf = 0; nf < 8; ++nf) {
                bf16x8 bh = *(const bf16x8*)(wbh + (nf * 16 + l15) * 8);
                bf16x8 bl = *(const bf16x8*)(wbl + (nf * 16 + l15) * 8);
                #pragma unroll
                for (int mf = 0; mf < 2; ++mf) {
                    acc[mf][nf] = __builtin_amdgcn_mfma_f32_16x16x32_bf16(ah[mf], bh, acc[mf][nf], 0, 0, 0);
                    acc[mf][nf] = __builtin_amdgcn_mfma_f32_16x16x32_bf16(ah[mf], bl, acc[mf][nf], 0, 0, 0);
                    acc[mf][nf] = __builtin_amdgcn_mfma_f32_16x16x32_bf16(al[mf], bh, acc[mf][nf], 0, 0, 0);
                }
            }
        }
    }

    // epilogue: D row(m) = (lane>>4)*4 + reg, col(n) = lane&15
    #pragma unroll
    for (int mf = 0; mf < 2; ++mf) {
        int mbase = wave * 32 + mf * 16 + sub * 4;
        #pragma unroll
        for (int nf = 0; nf < 8; ++nf) {
            int c = nf * 16 + l15;
            float s = sc[c], bb = bc[c];
            float v[4];
            #pragma unroll
            for (int rg = 0; rg < 4; ++rg) {
                int p = P0 + mbase + rg;
                float x = fmaxf(acc[mf][nf][rg] * s + bb, 0.f);
                v[rg] = (p >= 0 && p < CONVLEN) ? x : 0.f;
            }
            int i0 = (P0 + mbase + 1) >> 1;    // pooled index (P0 odd)
            float u0 = fmaxf(v[0], v[1]);
            float u1 = fmaxf(v[2], v[3]);
            if (i0 < POOLLEN)     outp[(size_t)i0 * 128 + c] = u0;
            if (i0 + 1 < POOLLEN) outp[(size_t)(i0 + 1) * 128 + c] = u1;
        }
    }
}

// =====================================================================
// conv2 (fused conv1+bn1+relu+pool1 recompute prologue) -> MFMA
// grid: rows_in_chunk * 6 tiles
// =====================================================================
__global__ __launch_bounds__(256)
void k_conv2_mfma(const float* __restrict__ X, const float* __restrict__ w1,
                  const float* __restrict__ bn1,
                  const short* __restrict__ Wt2hi, const short* __restrict__ Wt2lo,
                  const float* __restrict__ bn2, float* __restrict__ pool2t,
                  int b_off)
{
    const int blk = blockIdx.x;
    const int bl  = blk / 6, t = blk % 6;
    const int b   = b_off + bl;
    const int P0  = 128 * t - 1;          // conv2 position base (odd)
    const int T0  = 128 * t - 3;          // pool1 index base (= P0 - 2)
    const int X0  = 256 * t - 8;          // raw x base (= 2*T0 - 2)

    __shared__ __align__(16) float xw[264];
    __shared__ __align__(16) short t1h[130 * 64];
    __shared__ __align__(16) short t1l[130 * 64];
    __shared__ float sb1s[64], sb1b[64], sc2[128], bc2[128];

    const int tid = threadIdx.x;
    for (int g = tid; g < 262; g += 256) {
        int xi = X0 + g;
        xw[g] = (xi >= 0 && xi < L1X) ? X[(size_t)b * L1X + xi] : 0.f;
    }
    if (tid < 64) {
        float s = bn1[tid] * rsqrtf(bn1[192 + tid] + 1e-5f);
        sb1s[tid] = s;
        sb1b[tid] = bn1[64 + tid] - bn1[128 + tid] * s;
    }
    if (tid < 128) {
        float s = bn2[tid] * rsqrtf(bn2[384 + tid] + 1e-5f);
        sc2[tid] = s;
        bc2[tid] = bn2[128 + tid] - bn2[256 + tid] * s;
    }
    __syncthreads();

    // pool1 tile rows r=0..129 (t = T0+r), 64 channels, swizzled bf16 hi/lo
    for (int idx = tid; idx < 130 * 64; idx += 256) {
        int r = idx >> 6, c = idx & 63;
        int tt = T0 + r;
        float val = 0.f;
        if (tt >= 0 && tt <= 750) {
            float wk0 = w1[c * 3], wk1 = w1[c * 3 + 1], wk2 = w1[c * 3 + 2];
            float s = sb1s[c], bias = sb1b[c];
            float v0 = 0.f, v1 = 0.f;
            int li = 2 * r;   // xw local: conv pos 2tt-1 reads xw[li..li+2]
            if (tt >= 1)
                v0 = fmaxf((wk0 * xw[li] + wk1 * xw[li + 1] + wk2 * xw[li + 2]) * s + bias, 0.f);
            if (tt <= 749)
                v1 = fmaxf((wk0 * xw[li + 1] + wk1 * xw[li + 2] + wk2 * xw[li + 3]) * s + bias, 0.f);
            val = fmaxf(v0, v1);
        }
        short h = f2bf(val);
        int chunk = (c >> 3) ^ (r & 7);
        int off = r * 64 + chunk * 8 + (c & 7);
        t1h[off] = h;
        t1l[off] = f2bf(val - bf2f(h));
    }
    __syncthreads();

    conv_mfma_core<64, 2, 753, 377>(Wt2hi, Wt2lo, t1h, t1l, sc2, bc2,
                                    pool2t + (size_t)bl * L2P * 128, P0);
}

// =====================================================================
// conv3 MFMA. Input pool2t [row][pos][ic] fp32. grid: rows_in_chunk * 3
// =====================================================================
__global__ __launch_bounds__(256)
void k_conv3_mfma(const float* __restrict__ pool2t,
                  const short* __restrict__ Wt3hi, const short* __restrict__ Wt3lo,
                  const float* __restrict__ bn3, float* __restrict__ pool3t,
                  int b_off)
{
    const int blk = blockIdx.x;
    const int bl  = blk / 3, t = blk % 3;
    const int b   = b_off + bl;
    const int P0  = 128 * t - 1;          // conv3 position base (odd)
    const int I0  = 128 * t - 4;          // input (pool2) index base (= P0 - 3)

    __shared__ __align__(16) short t2h[130 * 128];
    __shared__ __align__(16) short t2l[130 * 128];
    __shared__ float sc3[128], bc3[128];

    const int tid = threadIdx.x;
    if (tid < 128) {
        float s = bn3[tid] * rsqrtf(bn3[384 + tid] + 1e-5f);
        sc3[tid] = s;
        bc3[tid] = bn3[128 + tid] - bn3[256 + tid] * s;
    }

    const float* src = pool2t + (size_t)bl * L2P * 128;
    for (int idx = tid; idx < 130 * 32; idx += 256) {   // 32 float4 per row
        int r = idx >> 5, q = idx & 31;                 // q: float4 idx, ic = q*4
        int pr = I0 + r;
        float4 v = make_float4(0.f, 0.f, 0.f, 0.f);
        if (pr >= 0 && pr < L2P) v = *(const float4*)(src + (size_t)pr * 128 + q * 4);
        int chunk = (q >> 1) ^ (r & 7);
        int off = r * 128 + chunk * 8 + (q & 1) * 4;
        *(short4*)(t2h + off) = make_short4(f2bf(v.x), f2bf(v.y), f2bf(v.z), f2bf(v.w));
        short l0 = f2bf(v.x - bf2f(f2bf(v.x)));
        short l1 = f2bf(v.y - bf2f(f2bf(v.y)));
        short l2 = f2bf(v.z - bf2f(f2bf(v.z)));
        short l3 = f2bf(v.w - bf2f(f2bf(v.w)));
        *(short4*)(t2l + off) = make_short4(l0, l1, l2, l3);
    }
    __syncthreads();

    conv_mfma_core<128, 4, 381, 191>(Wt3hi, Wt3lo, t2h, t2l, sc3, bc3,
                                     pool3t + (size_t)b * L3P * 128, P0);
}

// =====================================================================
// K4a: split-K GEMM partials: A[768, f'] @ Wperm; f' = i*128+c, W row = c*191+i
// tile 64x128, 256 thr, 4x8/thread, double-buffered. grid 12*2*32 = 768
// =====================================================================
__global__ __launch_bounds__(256)
void k_map2_gemm(const float* __restrict__ A, const float* __restrict__ W,
                 float* __restrict__ part)
{
    const int bid = blockIdx.x;
    const int kt  = bid / 24;
    const int rem = bid % 24;
    const int mt  = rem >> 1;
    const int nt  = rem & 1;

    __shared__ __align__(16) float At[2][4][64];
    __shared__ __align__(16) float Bt[2][4][128];

    const int tid = threadIdx.x;
    const int m0  = (tid & 15) * 4;
    const int n0  = (tid >> 4) * 8;

    const int arow = tid >> 2;
    const int akk  = tid & 3;
    const int bk   = tid >> 6;
    const int bc   = (tid & 63) * 2;

    const float* Aptr = A + (size_t)(mt * 64 + arow) * FEATK + kt * KCHUNK + akk;

    // B row permutation: logical k r -> W row (r&127)*191 + (r>>7)
    #define BROW(it) (W + (size_t)((((kt*KCHUNK + (it)*4 + bk) & 127) * 191 + \
                                    ((kt*KCHUNK + (it)*4 + bk) >> 7))) * D2 + nt*128 + bc)

    float acc[4][8];
    #pragma unroll
    for (int i = 0; i < 4; ++i)
        #pragma unroll
        for (int j = 0; j < 8; ++j) acc[i][j] = 0.f;

    float  a_reg = Aptr[0];
    float2 b_reg = *(const float2*)(BROW(0));
    At[0][akk][arow] = a_reg;
    *(float2*)&Bt[0][bk][bc] = b_reg;

    int cur = 0;
    for (int it = 0; it < NIT; ++it) {
        __syncthreads();
        if (it + 1 < NIT) {
            a_reg = Aptr[(it + 1) * 4];
            b_reg = *(const float2*)(BROW(it + 1));
        }
        #pragma unroll
        for (int k = 0; k < 4; ++k) {
            float4 a0 = *(const float4*)&At[cur][k][m0];
            float4 b0 = *(const float4*)&Bt[cur][k][n0];
            float4 b1 = *(const float4*)&Bt[cur][k][n0 + 4];
            float av[4] = {a0.x, a0.y, a0.z, a0.w};
            float bv[8] = {b0.x, b0.y, b0.z, b0.w, b1.x, b1.y, b1.z, b1.w};
            #pragma unroll
            for (int i = 0; i < 4; ++i)
                #pragma unroll
                for (int j = 0; j < 8; ++j)
                    acc[i][j] += av[i] * bv[j];
        }
        if (it + 1 < NIT) {
            At[cur ^ 1][akk][arow] = a_reg;
            *(float2*)&Bt[cur ^ 1][bk][bc] = b_reg;
        }
        cur ^= 1;
    }
    #undef BROW

    float* P = part + ((size_t)kt * 768) * D2;
    #pragma unroll
    for (int i = 0; i < 4; ++i) {
        int grow = mt * 64 + m0 + i;
        float* dst = P + (size_t)grow * D2 + nt * 128 + n0;
        *(float4*)(dst)     = make_float4(acc[i][0], acc[i][1], acc[i][2], acc[i][3]);
        *(float4*)(dst + 4) = make_float4(acc[i][4], acc[i][5], acc[i][6], acc[i][7]);
    }
}

// =====================================================================
// K4b: reduce split-K partials + bias + BN + positional encoding
// =====================================================================
__global__ __launch_bounds__(256)
void k_map2fin(const float* __restrict__ part, const float* __restrict__ mb,
               const float* __restrict__ bn, float* __restrict__ out)
{
    const int row = blockIdx.x;
    const int n   = threadIdx.x;
    float acc = 0.f;
    #pragma unroll
    for (int kt = 0; kt < SK; ++kt)
        acc += part[((size_t)kt * 768 + row) * D2 + n];

    float s    = bn[n] * rsqrtf(bn[768 + n] + 1e-5f);
    float beta = bn[256 + n];
    float mu   = bn[512 + n];
    float bias = mb[n];
    int   jj   = n >> 1;
    float freq = expf((float)(2 * jj) * (-4.605170185988092f / 256.f)); // -ln(100)/256
    int   t    = (row >> 2) % 6;
    float ang  = (float)t * freq;
    float pe   = (n & 1) ? cosf(ang) : sinf(ang);
    out[(size_t)row * D2 + n] = (acc + bias - mu) * s + beta + pe;
}

// =====================================================================
// K5: MPNN block (win=2). one block per graph, block 256
// =====================================================================
__global__ __launch_bounds__(256)
void k_mpnn(const float* __restrict__ a_pe, const float* __restrict__ gw,
            const float* __restrict__ gb, const float* __restrict__ bnA,
            const float* __restrict__ tw, const float* __restrict__ tb_,
            const float* __restrict__ bnM, float* __restrict__ feats,
            int nw, int stride, int base)
{
    const int g  = blockIdx.x;
    const int b  = g / nw, wi = g % nw;
    const int tid = threadIdx.x;

    __shared__ float Xc[8][256];
    __shared__ float Xb[8][256];
    __shared__ float Fs[8][256];
    __shared__ float Adj[8][8];
    __shared__ float hsm[8][128];

    for (int e = tid; e < 2048; e += 256) {
        int nn = e >> 8, d = e & 255;
        int tt = nn >> 2, sn = nn & 3;
        float v = a_pe[(((size_t)(b * 6) + (wi * stride + tt)) * 4 + sn) * D2 + d];
        Xc[nn][d] = v;
        float s = bnA[d] * rsqrtf(bnA[768 + d] + 1e-5f);
        Xb[nn][d] = (v - bnA[512 + d]) * s + bnA[256 + d];
    }
    __syncthreads();

    {   // f = Xc @ gw + gb
        const int d = tid;
        #pragma unroll
        for (int nn = 0; nn < 8; ++nn) {
            float acc = gb[d];
            for (int k = 0; k < 256; ++k) acc += Xc[nn][k] * gw[(size_t)k * D2 + d];
            Fs[nn][d] = acc;
        }
    }
    __syncthreads();

    if (tid < 64) {
        int nn = tid >> 3, m = tid & 7;
        float s = 0.f;
        for (int d = 0; d < 256; ++d) s += Fs[nn][d] * Fs[m][d];
        if (nn == m) s -= 1e8f;
        s = (s > 0.f) ? s : 0.01f * s;
        Adj[nn][m] = s;
    }
    __syncthreads();

    if (tid < 8) {
        int nn = tid;
        float mx = -1e30f;
        for (int m = 0; m < 8; ++m) mx = fmaxf(mx, Adj[nn][m]);
        float ex[8]; float sum = 0.f;
        for (int m = 0; m < 8; ++m) { ex[m] = expf(Adj[nn][m] - mx); sum += ex[m]; }
        float inv = 1.f / sum;
        for (int m = 0; m < 8; ++m) {
            float v = ex[m] * inv + ((nn == m) ? 1.f : 0.f);
            v *= ((nn >> 2) == (m >> 2)) ? 1.f : 0.7f;
            Adj[nn][m] = v;
        }
    }
    __syncthreads();

    {   // hmid = Adj @ Xb
        const int d = tid;
        float hm[8];
        #pragma unroll
        for (int nn = 0; nn < 8; ++nn) {
            float a = 0.f;
            #pragma unroll
            for (int m = 0; m < 8; ++m) a += Adj[nn][m] * Xb[m][d];
            hm[nn] = a;
        }
        #pragma unroll
        for (int nn = 0; nn < 8; ++nn) Fs[nn][d] = hm[nn];
    }
    __syncthreads();

    {   // h = leaky(BN(hmid @ tw + tb))
        const int o = tid & 127, half = tid >> 7;
        float ms  = bnM[o] * rsqrtf(bnM[384 + o] + 1e-5f);
        float mbe = bnM[128 + o], mmu = bnM[256 + o];
        #pragma unroll
        for (int q = 0; q < 4; ++q) {
            int nn = half + 2 * q;
            float acc = tb_[o];
            for (int d = 0; d < 256; ++d) acc += Fs[nn][d] * tw[(size_t)d * HIDN + o];
            float y = (acc - mmu) * ms + mbe;
            hsm[nn][o] = (y > 0.f) ? y : 0.01f * y;
        }
    }
    __syncthreads();

    for (int e = tid; e < 512; e += 256) {
        int sn = e >> 7, o = e & 127;
        feats[(size_t)b * 4096 + base + (wi * 4 + sn) * HIDN + o] =
            0.5f * (hsm[sn][o] + hsm[4 + sn][o]);
    }
}

// =====================================================================
// K6: FC head, one block per batch row
// =====================================================================
__global__ __launch_bounds__(256)
void k_fc(const float* __restrict__ feats,
          const float* __restrict__ w1f, const float* __restrict__ b1f,
          const float* __restrict__ w2f, const float* __restrict__ b2f,
          const float* __restrict__ w3f, const float* __restrict__ b3f,
          const float* __restrict__ w4f, const float* __restrict__ b4f,
          float* __restrict__ out)
{
    const int b = blockIdx.x;
    __shared__ float row[4096];
    __shared__ float h1[256], h2[256], h3[128];
    for (int e = threadIdx.x; e < 4096; e += 256) row[e] = feats[(size_t)b * 4096 + e];
    __syncthreads();
    const int n = threadIdx.x;
    {
        float acc = b1f[n];
        for (int f = 0; f < 4096; ++f) acc += row[f] * w1f[(size_t)f * 256 + n];
        h1[n] = fmaxf(acc, 0.f);
    }
    __syncthreads();
    {
        float acc = b2f[n];
        for (int k = 0; k < 256; ++k) acc += h1[k] * w2f[(size_t)k * 256 + n];
        h2[n] = fmaxf(acc, 0.f);
    }
    __syncthreads();
    if (n < 128) {
        float acc = b3f[n];
        for (int k = 0; k < 256; ++k) acc += h2[k] * w3f[(size_t)k * 128 + n];
        h3[n] = fmaxf(acc, 0.f);
    }
    __syncthreads();
    if (n < 5) {
        float acc = b4f[n];
        for (int k = 0; k < 128; ++k) acc += h3[k] * w4f[(size_t)k * 5 + n];
        out[b * 5 + n] = acc;
    }
}

// =====================================================================
extern "C" void kernel_launch(void* const* d_in, const int* in_sizes, int n_in,
                              void* d_out, int out_size, void* d_ws, size_t ws_size,
                              hipStream_t stream)
{
    const float* X      = (const float*)d_in[0];
    const float* w1     = (const float*)d_in[1];
    const float* bn1    = (const float*)d_in[2];
    const float* w2     = (const float*)d_in[3];
    const float* bn2    = (const float*)d_in[4];
    const float* w3     = (const float*)d_in[5];
    const float* bn3    = (const float*)d_in[6];
    const float* map2w  = (const float*)d_in[7];
    const float* map2b  = (const float*)d_in[8];
    const float* bnm2   = (const float*)d_in[9];
    const float* g1w    = (const float*)d_in[10];
    const float* g1b    = (const float*)d_in[11];
    const float* bnA1   = (const float*)d_in[12];
    const float* th1w   = (const float*)d_in[13];
    const float* th1b   = (const float*)d_in[14];
    const float* bnM1   = (const float*)d_in[15];
    const float* g2w    = (const float*)d_in[16];
    const float* g2b    = (const float*)d_in[17];
    const float* bnA2   = (const float*)d_in[18];
    const float* th2w   = (const float*)d_in[19];
    const float* th2b   = (const float*)d_in[20];
    const float* bnM2   = (const float*)d_in[21];
    const float* fc1w   = (const float*)d_in[22];
    const float* fc1b   = (const float*)d_in[23];
    const float* fc2w   = (const float*)d_in[24];
    const float* fc2b   = (const float*)d_in[25];
    const float* fc3w   = (const float*)d_in[26];
    const float* fc3b   = (const float*)d_in[27];
    const float* fc4w   = (const float*)d_in[28];
    const float* fc4b   = (const float*)d_in[29];
    float* out = (float*)d_out;

    float* ws = (float*)d_ws;
    const size_t N_P2C = (size_t)192 * L2P * 128;   // 9,265,152 floats (pool2t, per chunk)
    const size_t N_P3  = (size_t)768 * L3P * 128;   // 18,776,064 floats (pool3t)
    float* pool2t = ws;
    float* pool3t = ws + N_P2C;
    float* a_pe   = pool3t + N_P3;
    float* feats  = a_pe + (size_t)768 * D2;
    short* Wt2hi  = (short*)(feats + (size_t)32 * 4096);
    short* Wt2lo  = Wt2hi + 24576;
    short* Wt3hi  = Wt2lo + 24576;
    short* Wt3lo  = Wt3hi + 49152;
    // split-K partials alias pool2t (free after conv loop): 6.29M < 9.27M floats
    float* part   = ws;

    k_wprep<64, 2><<<96, 256, 0, stream>>>(w2, Wt2hi, Wt2lo);
    k_wprep<128, 4><<<192, 256, 0, stream>>>(w3, Wt3hi, Wt3lo);

    for (int boff = 0; boff < 768; boff += 192) {
        k_conv2_mfma<<<192 * 6, 256, 0, stream>>>(X, w1, bn1, Wt2hi, Wt2lo, bn2,
                                                  pool2t, boff);
        k_conv3_mfma<<<192 * 3, 256, 0, stream>>>(pool2t, Wt3hi, Wt3lo, bn3,
                                                  pool3t, boff);
    }
    k_map2_gemm<<<768, 256, 0, stream>>>(pool3t, map2w, part);
    k_map2fin<<<768, 256, 0, stream>>>(part, map2b, bnm2, a_pe);
    k_mpnn<<<160, 256, 0, stream>>>(a_pe, g1w, g1b, bnA1, th1w, th1b, bnM1,
                                    feats, 5, 1, 0);
    k_mpnn<<<96, 256, 0, stream>>>(a_pe, g2w, g2b, bnA2, th2w, th2b, bnM2,
                                   feats, 3, 2, 2560);
    k_fc<<<32, 256, 0, stream>>>(feats, fc1w, fc1b, fc2w, fc2b, fc3w, fc3b,
                                 fc4w, fc4b, out);
}

// Round 6
// 717.875 us; speedup vs baseline: 2.6186x; 1.1014x over previous
//
#include <hip/hip_runtime.h>
#include <hip/hip_bf16.h>

// ---------------- constants ----------------
#define L1X   1500   // raw sequence length
#define L1P   751    // pool1 length (t in [0,750])
#define C1    64
#define L2P   377    // pool2 length
#define C2    128
#define L3P   191    // pool3 length
#define C3    128
#define FEATK 24448  // L3P*C3 (stored [i][c] -> f' = i*128 + c)
#define D2    256
#define HIDN  128

// map2 GEMM config
#define SK      32            // split-K ways
#define KCHUNK  764           // FEATK / SK = 191*4
#define NIT     191           // KCHUNK / 4

typedef __attribute__((ext_vector_type(8))) short bf16x8;
typedef __attribute__((ext_vector_type(4))) float f32x4;

__device__ __forceinline__ short f2bf(float x) {
    union { float f; unsigned u; } v; v.f = x;
    unsigned r = (v.u + 0x7FFFu + ((v.u >> 16) & 1u)) >> 16;
    return (short)r;
}
__device__ __forceinline__ float bf2f(short s) {
    union { float f; unsigned u; } v; v.u = ((unsigned)(unsigned short)s) << 16;
    return v.f;
}

// =====================================================================
// Weight prep: w[OC=128][IC][3] fp32 -> Wt[tap][kb][sub][c][8] bf16 hi/lo
// =====================================================================
template<int IC, int KB>
__global__ __launch_bounds__(256)
void k_wprep(const float* __restrict__ w, short* __restrict__ WtHi,
             short* __restrict__ WtLo)
{
    int idx = blockIdx.x * 256 + threadIdx.x;
    if (idx >= 3 * KB * 4 * 128 * 8) return;
    int i    = idx & 7;
    int rest = idx >> 3;
    int c    = rest & 127; rest >>= 7;
    int sub  = rest & 3;   rest >>= 2;
    int kb   = rest % KB;
    int tap  = rest / KB;
    int ic   = kb * 32 + sub * 8 + i;
    float x  = w[(c * IC + ic) * 3 + tap];
    short h  = f2bf(x);
    WtHi[idx] = h;
    WtLo[idx] = f2bf(x - bf2f(h));
}

// =====================================================================
// Shared MFMA conv core (see round-4 comments).
// =====================================================================
template<int IC, int KB, int CONVLEN, int POOLLEN>
__device__ __forceinline__
void conv_mfma_core(const short* __restrict__ WtHi, const short* __restrict__ WtLo,
                    const short* lhi, const short* llo,
                    const float* sc, const float* bc,
                    float* __restrict__ outp, int P0)
{
    const int lane = threadIdx.x & 63;
    const int wave = threadIdx.x >> 6;
    const int l15  = lane & 15;
    const int sub  = lane >> 4;

    f32x4 acc[2][8];
    #pragma unroll
    for (int mf = 0; mf < 2; ++mf)
        #pragma unroll
        for (int nf = 0; nf < 8; ++nf)
            acc[mf][nf] = (f32x4){0.f, 0.f, 0.f, 0.f};

    #pragma unroll
    for (int tap = 0; tap < 3; ++tap) {
        #pragma unroll
        for (int kb = 0; kb < KB; ++kb) {
            bf16x8 ah[2], al[2];
            #pragma unroll
            for (int mf = 0; mf < 2; ++mf) {
                int r = wave * 32 + mf * 16 + l15 + tap;      // LDS input row
                int chunk = (kb * 4 + sub) ^ (r & 7);
                int off = r * IC + chunk * 8;
                ah[mf] = *(const bf16x8*)(lhi + off);
                al[mf] = *(const bf16x8*)(llo + off);
            }
            const short* wbh = WtHi + (size_t)(((tap * KB + kb) * 4 + sub) * 128) * 8;
            const short* wbl = WtLo + (size_t)(((tap * KB + kb) * 4 + sub) * 128) * 8;
            #pragma unroll
            for (int nf = 0; nf < 8; ++nf) {
                bf16x8 bh = *(const bf16x8*)(wbh + (nf * 16 + l15) * 8);
                bf16x8 bl = *(const bf16x8*)(wbl + (nf * 16 + l15) * 8);
                #pragma unroll
                for (int mf = 0; mf < 2; ++mf) {
                    acc[mf][nf] = __builtin_amdgcn_mfma_f32_16x16x32_bf16(ah[mf], bh, acc[mf][nf], 0, 0, 0);
                    acc[mf][nf] = __builtin_amdgcn_mfma_f32_16x16x32_bf16(ah[mf], bl, acc[mf][nf], 0, 0, 0);
                    acc[mf][nf] = __builtin_amdgcn_mfma_f32_16x16x32_bf16(al[mf], bh, acc[mf][nf], 0, 0, 0);
                }
            }
        }
    }

    #pragma unroll
    for (int mf = 0; mf < 2; ++mf) {
        int mbase = wave * 32 + mf * 16 + sub * 4;
        #pragma unroll
        for (int nf = 0; nf < 8; ++nf) {
            int c = nf * 16 + l15;
            float s = sc[c], bb = bc[c];
            float v[4];
            #pragma unroll
            for (int rg = 0; rg < 4; ++rg) {
                int p = P0 + mbase + rg;
                float x = fmaxf(acc[mf][nf][rg] * s + bb, 0.f);
                v[rg] = (p >= 0 && p < CONVLEN) ? x : 0.f;
            }
            int i0 = (P0 + mbase + 1) >> 1;    // pooled index (P0 odd)
            float u0 = fmaxf(v[0], v[1]);
            float u1 = fmaxf(v[2], v[3]);
            if (i0 < POOLLEN)     outp[(size_t)i0 * 128 + c] = u0;
            if (i0 + 1 < POOLLEN) outp[(size_t)(i0 + 1) * 128 + c] = u1;
        }
    }
}

// =====================================================================
// conv2 (fused conv1+bn1+relu+pool1 recompute prologue) -> MFMA
// =====================================================================
__global__ __launch_bounds__(256)
void k_conv2_mfma(const float* __restrict__ X, const float* __restrict__ w1,
                  const float* __restrict__ bn1,
                  const short* __restrict__ Wt2hi, const short* __restrict__ Wt2lo,
                  const float* __restrict__ bn2, float* __restrict__ pool2t,
                  int b_off)
{
    const int blk = blockIdx.x;
    const int bl  = blk / 6, t = blk % 6;
    const int b   = b_off + bl;
    const int P0  = 128 * t - 1;
    const int T0  = 128 * t - 3;
    const int X0  = 256 * t - 8;

    __shared__ __align__(16) float xw[264];
    __shared__ __align__(16) short t1h[130 * 64];
    __shared__ __align__(16) short t1l[130 * 64];
    __shared__ float sb1s[64], sb1b[64], sc2[128], bc2[128];

    const int tid = threadIdx.x;
    for (int g = tid; g < 262; g += 256) {
        int xi = X0 + g;
        xw[g] = (xi >= 0 && xi < L1X) ? X[(size_t)b * L1X + xi] : 0.f;
    }
    if (tid < 64) {
        float s = bn1[tid] * rsqrtf(bn1[192 + tid] + 1e-5f);
        sb1s[tid] = s;
        sb1b[tid] = bn1[64 + tid] - bn1[128 + tid] * s;
    }
    if (tid < 128) {
        float s = bn2[tid] * rsqrtf(bn2[384 + tid] + 1e-5f);
        sc2[tid] = s;
        bc2[tid] = bn2[128 + tid] - bn2[256 + tid] * s;
    }
    __syncthreads();

    for (int idx = tid; idx < 130 * 64; idx += 256) {
        int r = idx >> 6, c = idx & 63;
        int tt = T0 + r;
        float val = 0.f;
        if (tt >= 0 && tt <= 750) {
            float wk0 = w1[c * 3], wk1 = w1[c * 3 + 1], wk2 = w1[c * 3 + 2];
            float s = sb1s[c], bias = sb1b[c];
            float v0 = 0.f, v1 = 0.f;
            int li = 2 * r;
            if (tt >= 1)
                v0 = fmaxf((wk0 * xw[li] + wk1 * xw[li + 1] + wk2 * xw[li + 2]) * s + bias, 0.f);
            if (tt <= 749)
                v1 = fmaxf((wk0 * xw[li + 1] + wk1 * xw[li + 2] + wk2 * xw[li + 3]) * s + bias, 0.f);
            val = fmaxf(v0, v1);
        }
        short h = f2bf(val);
        int chunk = (c >> 3) ^ (r & 7);
        int off = r * 64 + chunk * 8 + (c & 7);
        t1h[off] = h;
        t1l[off] = f2bf(val - bf2f(h));
    }
    __syncthreads();

    conv_mfma_core<64, 2, 753, 377>(Wt2hi, Wt2lo, t1h, t1l, sc2, bc2,
                                    pool2t + (size_t)bl * L2P * 128, P0);
}

// =====================================================================
// conv3 MFMA. Input pool2t [row][pos][ic] fp32. grid: rows_in_chunk * 3
// =====================================================================
__global__ __launch_bounds__(256)
void k_conv3_mfma(const float* __restrict__ pool2t,
                  const short* __restrict__ Wt3hi, const short* __restrict__ Wt3lo,
                  const float* __restrict__ bn3, float* __restrict__ pool3t,
                  int b_off)
{
    const int blk = blockIdx.x;
    const int bl  = blk / 3, t = blk % 3;
    const int b   = b_off + bl;
    const int P0  = 128 * t - 1;
    const int I0  = 128 * t - 4;

    __shared__ __align__(16) short t2h[130 * 128];
    __shared__ __align__(16) short t2l[130 * 128];
    __shared__ float sc3[128], bc3[128];

    const int tid = threadIdx.x;
    if (tid < 128) {
        float s = bn3[tid] * rsqrtf(bn3[384 + tid] + 1e-5f);
        sc3[tid] = s;
        bc3[tid] = bn3[128 + tid] - bn3[256 + tid] * s;
    }

    const float* src = pool2t + (size_t)bl * L2P * 128;
    for (int idx = tid; idx < 130 * 32; idx += 256) {
        int r = idx >> 5, q = idx & 31;
        int pr = I0 + r;
        float4 v = make_float4(0.f, 0.f, 0.f, 0.f);
        if (pr >= 0 && pr < L2P) v = *(const float4*)(src + (size_t)pr * 128 + q * 4);
        int chunk = (q >> 1) ^ (r & 7);
        int off = r * 128 + chunk * 8 + (q & 1) * 4;
        *(short4*)(t2h + off) = make_short4(f2bf(v.x), f2bf(v.y), f2bf(v.z), f2bf(v.w));
        short l0 = f2bf(v.x - bf2f(f2bf(v.x)));
        short l1 = f2bf(v.y - bf2f(f2bf(v.y)));
        short l2 = f2bf(v.z - bf2f(f2bf(v.z)));
        short l3 = f2bf(v.w - bf2f(f2bf(v.w)));
        *(short4*)(t2l + off) = make_short4(l0, l1, l2, l3);
    }
    __syncthreads();

    conv_mfma_core<128, 4, 381, 191>(Wt3hi, Wt3lo, t2h, t2l, sc3, bc3,
                                     pool3t + (size_t)b * L3P * 128, P0);
}

// =====================================================================
// K4a: split-K GEMM partials. tile 64x128, double-buffered, At padded
// stride 68 to kill the 4-way store bank conflict (bank=(4*akk+arow)%32).
// =====================================================================
__global__ __launch_bounds__(256)
void k_map2_gemm(const float* __restrict__ A, const float* __restrict__ W,
                 float* __restrict__ part)
{
    const int bid = blockIdx.x;
    const int kt  = bid / 24;
    const int rem = bid % 24;
    const int mt  = rem >> 1;
    const int nt  = rem & 1;

    __shared__ __align__(16) float At[2][4][68];
    __shared__ __align__(16) float Bt[2][4][128];

    const int tid = threadIdx.x;
    const int m0  = (tid & 15) * 4;
    const int n0  = (tid >> 4) * 8;

    const int arow = tid >> 2;
    const int akk  = tid & 3;
    const int bk   = tid >> 6;
    const int bc   = (tid & 63) * 2;

    const float* Aptr = A + (size_t)(mt * 64 + arow) * FEATK + kt * KCHUNK + akk;

    #define BROW(it) (W + (size_t)((((kt*KCHUNK + (it)*4 + bk) & 127) * 191 + \
                                    ((kt*KCHUNK + (it)*4 + bk) >> 7))) * D2 + nt*128 + bc)

    float acc[4][8];
    #pragma unroll
    for (int i = 0; i < 4; ++i)
        #pragma unroll
        for (int j = 0; j < 8; ++j) acc[i][j] = 0.f;

    float  a_reg = Aptr[0];
    float2 b_reg = *(const float2*)(BROW(0));
    At[0][akk][arow] = a_reg;
    *(float2*)&Bt[0][bk][bc] = b_reg;

    int cur = 0;
    for (int it = 0; it < NIT; ++it) {
        __syncthreads();
        if (it + 1 < NIT) {
            a_reg = Aptr[(it + 1) * 4];
            b_reg = *(const float2*)(BROW(it + 1));
        }
        #pragma unroll
        for (int k = 0; k < 4; ++k) {
            float4 a0 = *(const float4*)&At[cur][k][m0];
            float4 b0 = *(const float4*)&Bt[cur][k][n0];
            float4 b1 = *(const float4*)&Bt[cur][k][n0 + 4];
            float av[4] = {a0.x, a0.y, a0.z, a0.w};
            float bv[8] = {b0.x, b0.y, b0.z, b0.w, b1.x, b1.y, b1.z, b1.w};
            #pragma unroll
            for (int i = 0; i < 4; ++i)
                #pragma unroll
                for (int j = 0; j < 8; ++j)
                    acc[i][j] += av[i] * bv[j];
        }
        if (it + 1 < NIT) {
            At[cur ^ 1][akk][arow] = a_reg;
            *(float2*)&Bt[cur ^ 1][bk][bc] = b_reg;
        }
        cur ^= 1;
    }
    #undef BROW

    float* P = part + ((size_t)kt * 768) * D2;
    #pragma unroll
    for (int i = 0; i < 4; ++i) {
        int grow = mt * 64 + m0 + i;
        float* dst = P + (size_t)grow * D2 + nt * 128 + n0;
        *(float4*)(dst)     = make_float4(acc[i][0], acc[i][1], acc[i][2], acc[i][3]);
        *(float4*)(dst + 4) = make_float4(acc[i][4], acc[i][5], acc[i][6], acc[i][7]);
    }
}

// =====================================================================
// K4b: reduce split-K partials + bias + BN + positional encoding
// =====================================================================
__global__ __launch_bounds__(256)
void k_map2fin(const float* __restrict__ part, const float* __restrict__ mb,
               const float* __restrict__ bn, float* __restrict__ out)
{
    const int row = blockIdx.x;
    const int n   = threadIdx.x;
    float acc = 0.f;
    #pragma unroll
    for (int kt = 0; kt < SK; ++kt)
        acc += part[((size_t)kt * 768 + row) * D2 + n];

    float s    = bn[n] * rsqrtf(bn[768 + n] + 1e-5f);
    float beta = bn[256 + n];
    float mu   = bn[512 + n];
    float bias = mb[n];
    int   jj   = n >> 1;
    float freq = expf((float)(2 * jj) * (-4.605170185988092f / 256.f)); // -ln(100)/256
    int   t    = (row >> 2) % 6;
    float ang  = (float)t * freq;
    float pe   = (n & 1) ? cosf(ang) : sinf(ang);
    out[(size_t)row * D2 + n] = (acc + bias - mu) * s + beta + pe;
}

// =====================================================================
// K5: MPNN block (win=2). one block per graph, block 256
// =====================================================================
__global__ __launch_bounds__(256)
void k_mpnn(const float* __restrict__ a_pe, const float* __restrict__ gw,
            const float* __restrict__ gb, const float* __restrict__ bnA,
            const float* __restrict__ tw, const float* __restrict__ tb_,
            const float* __restrict__ bnM, float* __restrict__ feats,
            int nw, int stride, int base)
{
    const int g  = blockIdx.x;
    const int b  = g / nw, wi = g % nw;
    const int tid = threadIdx.x;

    __shared__ float Xc[8][256];
    __shared__ float Xb[8][256];
    __shared__ float Fs[8][256];
    __shared__ float Adj[8][8];
    __shared__ float hsm[8][128];

    for (int e = tid; e < 2048; e += 256) {
        int nn = e >> 8, d = e & 255;
        int tt = nn >> 2, sn = nn & 3;
        float v = a_pe[(((size_t)(b * 6) + (wi * stride + tt)) * 4 + sn) * D2 + d];
        Xc[nn][d] = v;
        float s = bnA[d] * rsqrtf(bnA[768 + d] + 1e-5f);
        Xb[nn][d] = (v - bnA[512 + d]) * s + bnA[256 + d];
    }
    __syncthreads();

    {   // f = Xc @ gw + gb
        const int d = tid;
        #pragma unroll
        for (int nn = 0; nn < 8; ++nn) {
            float acc = gb[d];
            for (int k = 0; k < 256; ++k) acc += Xc[nn][k] * gw[(size_t)k * D2 + d];
            Fs[nn][d] = acc;
        }
    }
    __syncthreads();

    if (tid < 64) {
        int nn = tid >> 3, m = tid & 7;
        float s = 0.f;
        for (int d = 0; d < 256; ++d) s += Fs[nn][d] * Fs[m][d];
        if (nn == m) s -= 1e8f;
        s = (s > 0.f) ? s : 0.01f * s;
        Adj[nn][m] = s;
    }
    __syncthreads();

    if (tid < 8) {
        int nn = tid;
        float mx = -1e30f;
        for (int m = 0; m < 8; ++m) mx = fmaxf(mx, Adj[nn][m]);
        float ex[8]; float sum = 0.f;
        for (int m = 0; m < 8; ++m) { ex[m] = expf(Adj[nn][m] - mx); sum += ex[m]; }
        float inv = 1.f / sum;
        for (int m = 0; m < 8; ++m) {
            float v = ex[m] * inv + ((nn == m) ? 1.f : 0.f);
            v *= ((nn >> 2) == (m >> 2)) ? 1.f : 0.7f;
            Adj[nn][m] = v;
        }
    }
    __syncthreads();

    {   // hmid = Adj @ Xb
        const int d = tid;
        float hm[8];
        #pragma unroll
        for (int nn = 0; nn < 8; ++nn) {
            float a = 0.f;
            #pragma unroll
            for (int m = 0; m < 8; ++m) a += Adj[nn][m] * Xb[m][d];
            hm[nn] = a;
        }
        #pragma unroll
        for (int nn = 0; nn < 8; ++nn) Fs[nn][d] = hm[nn];
    }
    __syncthreads();

    {   // h = leaky(BN(hmid @ tw + tb))
        const int o = tid & 127, half = tid >> 7;
        float ms  = bnM[o] * rsqrtf(bnM[384 + o] + 1e-5f);
        float mbe = bnM[128 + o], mmu = bnM[256 + o];
        #pragma unroll
        for (int q = 0; q < 4; ++q) {
            int nn = half + 2 * q;
            float acc = tb_[o];
            for (int d = 0; d < 256; ++d) acc += Fs[nn][d] * tw[(size_t)d * HIDN + o];
            float y = (acc - mmu) * ms + mbe;
            hsm[nn][o] = (y > 0.f) ? y : 0.01f * y;
        }
    }
    __syncthreads();

    for (int e = tid; e < 512; e += 256) {
        int sn = e >> 7, o = e & 127;
        feats[(size_t)b * 4096 + base + (wi * 4 + sn) * HIDN + o] =
            0.5f * (hsm[sn][o] + hsm[4 + sn][o]);
    }
}

// =====================================================================
// K6a: fc1 split-K. grid = 16 k-chunks x 8 n-chunks = 128 blocks.
// Each block: all 32 rows x 32 cols x 256-K chunk -> partial.
// =====================================================================
__global__ __launch_bounds__(256)
void k_fc1(const float* __restrict__ feats, const float* __restrict__ w1f,
           float* __restrict__ partfc)
{
    const int kc = blockIdx.x >> 3;       // 0..15
    const int nc = blockIdx.x & 7;        // 0..7
    const int tid = threadIdx.x;

    __shared__ float fst[32 * 257];       // padded: bank varies with row

    for (int idx = tid; idx < 32 * 256; idx += 256) {
        int r = idx >> 8, k = idx & 255;
        fst[r * 257 + k] = feats[(size_t)r * 4096 + kc * 256 + k];
    }
    __syncthreads();

    const int c  = tid & 31;              // col within chunk
    const int rg = tid >> 5;              // row group 0..7 (4 rows each)
    const float* wp = w1f + (size_t)(kc * 256) * 256 + nc * 32 + c;

    float acc[4] = {0.f, 0.f, 0.f, 0.f};
    for (int k = 0; k < 256; ++k) {
        float wv = wp[(size_t)k * 256];
        #pragma unroll
        for (int j = 0; j < 4; ++j)
            acc[j] += fst[(rg * 4 + j) * 257 + k] * wv;
    }
    #pragma unroll
    for (int j = 0; j < 4; ++j)
        partfc[((size_t)kc * 32 + rg * 4 + j) * 256 + nc * 32 + c] = acc[j];
}

// =====================================================================
// K6b: reduce fc1 partials + relu, then fc2/fc3/fc4. one block per row.
// =====================================================================
__global__ __launch_bounds__(256)
void k_fc_rest(const float* __restrict__ partfc,
               const float* __restrict__ b1f,
               const float* __restrict__ w2f, const float* __restrict__ b2f,
               const float* __restrict__ w3f, const float* __restrict__ b3f,
               const float* __restrict__ w4f, const float* __restrict__ b4f,
               float* __restrict__ out)
{
    const int b = blockIdx.x;
    const int n = threadIdx.x;
    __shared__ float h1[256], h2[256], h3[128];

    {
        float acc = b1f[n];
        #pragma unroll
        for (int kc = 0; kc < 16; ++kc)
            acc += partfc[((size_t)kc * 32 + b) * 256 + n];
        h1[n] = fmaxf(acc, 0.f);
    }
    __syncthreads();
    {
        float acc = b2f[n];
        for (int k = 0; k < 256; ++k) acc += h1[k] * w2f[(size_t)k * 256 + n];
        h2[n] = fmaxf(acc, 0.f);
    }
    __syncthreads();
    if (n < 128) {
        float acc = b3f[n];
        for (int k = 0; k < 256; ++k) acc += h2[k] * w3f[(size_t)k * 128 + n];
        h3[n] = fmaxf(acc, 0.f);
    }
    __syncthreads();
    if (n < 5) {
        float acc = b4f[n];
        for (int k = 0; k < 128; ++k) acc += h3[k] * w4f[(size_t)k * 5 + n];
        out[b * 5 + n] = acc;
    }
}

// =====================================================================
extern "C" void kernel_launch(void* const* d_in, const int* in_sizes, int n_in,
                              void* d_out, int out_size, void* d_ws, size_t ws_size,
                              hipStream_t stream)
{
    const float* X      = (const float*)d_in[0];
    const float* w1     = (const float*)d_in[1];
    const float* bn1    = (const float*)d_in[2];
    const float* w2     = (const float*)d_in[3];
    const float* bn2    = (const float*)d_in[4];
    const float* w3     = (const float*)d_in[5];
    const float* bn3    = (const float*)d_in[6];
    const float* map2w  = (const float*)d_in[7];
    const float* map2b  = (const float*)d_in[8];
    const float* bnm2   = (const float*)d_in[9];
    const float* g1w    = (const float*)d_in[10];
    const float* g1b    = (const float*)d_in[11];
    const float* bnA1   = (const float*)d_in[12];
    const float* th1w   = (const float*)d_in[13];
    const float* th1b   = (const float*)d_in[14];
    const float* bnM1   = (const float*)d_in[15];
    const float* g2w    = (const float*)d_in[16];
    const float* g2b    = (const float*)d_in[17];
    const float* bnA2   = (const float*)d_in[18];
    const float* th2w   = (const float*)d_in[19];
    const float* th2b   = (const float*)d_in[20];
    const float* bnM2   = (const float*)d_in[21];
    const float* fc1w   = (const float*)d_in[22];
    const float* fc1b   = (const float*)d_in[23];
    const float* fc2w   = (const float*)d_in[24];
    const float* fc2b   = (const float*)d_in[25];
    const float* fc3w   = (const float*)d_in[26];
    const float* fc3b   = (const float*)d_in[27];
    const float* fc4w   = (const float*)d_in[28];
    const float* fc4b   = (const float*)d_in[29];
    float* out = (float*)d_out;

    float* ws = (float*)d_ws;
    const size_t N_P2C = (size_t)192 * L2P * 128;   // pool2t per chunk
    const size_t N_P3  = (size_t)768 * L3P * 128;   // pool3t
    float* pool2t = ws;
    float* pool3t = ws + N_P2C;
    float* a_pe   = pool3t + N_P3;
    float* feats  = a_pe + (size_t)768 * D2;
    short* Wt2hi  = (short*)(feats + (size_t)32 * 4096);
    short* Wt2lo  = Wt2hi + 24576;
    short* Wt3hi  = Wt2lo + 24576;
    short* Wt3lo  = Wt3hi + 49152;
    float* partfc = (float*)(Wt3lo + 49152);        // 16*32*256 floats
    // split-K partials alias pool2t (free after conv loop)
    float* part   = ws;

    k_wprep<64, 2><<<96, 256, 0, stream>>>(w2, Wt2hi, Wt2lo);
    k_wprep<128, 4><<<192, 256, 0, stream>>>(w3, Wt3hi, Wt3lo);

    for (int boff = 0; boff < 768; boff += 192) {
        k_conv2_mfma<<<192 * 6, 256, 0, stream>>>(X, w1, bn1, Wt2hi, Wt2lo, bn2,
                                                  pool2t, boff);
        k_conv3_mfma<<<192 * 3, 256, 0, stream>>>(pool2t, Wt3hi, Wt3lo, bn3,
                                                  pool3t, boff);
    }
    k_map2_gemm<<<768, 256, 0, stream>>>(pool3t, map2w, part);
    k_map2fin<<<768, 256, 0, stream>>>(part, map2b, bnm2, a_pe);
    k_mpnn<<<160, 256, 0, stream>>>(a_pe, g1w, g1b, bnA1, th1w, th1b, bnM1,
                                    feats, 5, 1, 0);
    k_mpnn<<<96, 256, 0, stream>>>(a_pe, g2w, g2b, bnA2, th2w, th2b, bnM2,
                                   feats, 3, 2, 2560);
    k_fc1<<<128, 256, 0, stream>>>(feats, fc1w, partfc);
    k_fc_rest<<<32, 256, 0, stream>>>(partfc, fc1b, fc2w, fc2b, fc3w, fc3b,
                                      fc4w, fc4b, out);
}